// Round 4
// baseline (717.933 us; speedup 1.0000x reference)
//
#include <hip/hip_runtime.h>
#include <hip/hip_bf16.h>

// Problem constants (from reference setup_inputs)
#define B_    8
#define N_    8192
#define C_    512
#define H_    8
#define HD_   64
#define M_    (B_ * N_)      // 65536 rows
#define TWO_C 1024

typedef short short8 __attribute__((ext_vector_type(8)));   // 8 bf16 (4 VGPRs)
typedef float f32x4  __attribute__((ext_vector_type(4)));   // MFMA accumulator

__device__ __forceinline__ float bf2f(unsigned v) {
    return __uint_as_float(v << 16);
}

__device__ __forceinline__ unsigned f2bf(float f) {
    union { __hip_bfloat16 b; unsigned short u; } cv;
    cv.b = __float2bfloat16(f);
    return (unsigned)cv.u;
}

__device__ __forceinline__ uint2 pack4(float4 f) {
    uint2 r;
    r.x = f2bf(f.x) | (f2bf(f.y) << 16);
    r.y = f2bf(f.z) | (f2bf(f.w) << 16);
    return r;
}

// ---------------------------------------------------------------------------
// Kernel 0a: qk_w fp32 -> bf16 (1MB out).  Kernel 0b: x fp32 -> bf16 (64MB out,
// lives in d_out which is dead until out_mfma overwrites it).
// Removes the 8x-duplicated per-block fp32->bf16 pack from the GEMM and
// halves the GEMM's A-operand HBM fetch.
// ---------------------------------------------------------------------------
__global__ __launch_bounds__(256) void conv_w_bf16(
    const float* __restrict__ w, unsigned short* __restrict__ wbf)
{
    const int i = (blockIdx.x * 256 + threadIdx.x) * 8;
    float4 a = *(const float4*)(w + i);
    float4 b = *(const float4*)(w + i + 4);
    uint2 pa = pack4(a), pb = pack4(b);
    *(uint4*)(wbf + i) = make_uint4(pa.x, pa.y, pb.x, pb.y);
}

__global__ __launch_bounds__(256) void conv_x_bf16(
    const float* __restrict__ x, unsigned short* __restrict__ xbf)
{
    const size_t i = ((size_t)blockIdx.x * 256 + threadIdx.x) * 8;
    float4 a = *(const float4*)(x + i);
    float4 b = *(const float4*)(x + i + 4);
    uint2 pa = pack4(a), pb = pack4(b);
    *(uint4*)(xbf + i) = make_uint4(pa.x, pa.y, pb.x, pb.y);
}

// ---------------------------------------------------------------------------
// Kernel 1: qk = x @ qk_w^T + qk_b ; q = elu(.)+1 ; k = elu(.)+1  (bf16 out)
// MFMA bf16 GEMM: 128x128 tile, BK=64, 4 waves (2x2), 4x4 16x16x32 per wave.
// Reg-staged (uint4 global load -> ds_write_b128), issue-early/write-late so
// HBM latency hides under the previous iteration's MFMAs.
// LDS XOR swizzle (both sides in LDS addressing): slot q of row r holds
// global granule q^(r&7); fragment read uses slot=(kk*4+qg)^(fr&7).
// 128B rows -> each 8-lane group covers all 8 bank-quads: conflict-free.
// XCD swizzle: all 8 column tiles of a row panel land on the same XCD
// (xcd = L&7 = rp%8 under round-robin dispatch), x panel L2-resident.
// ---------------------------------------------------------------------------
__global__ __launch_bounds__(256, 2) void gemm_qk_mfma(
    const unsigned short* __restrict__ xbf, const unsigned short* __restrict__ wbf,
    const float* __restrict__ bias,
    __hip_bfloat16* __restrict__ qws, __hip_bfloat16* __restrict__ kws)
{
    __shared__ __align__(16) unsigned short As[128 * 64];  // [row][k] bf16, 16KB
    __shared__ __align__(16) unsigned short Bs[128 * 64];

    const int t  = threadIdx.x;
    const int wv = t >> 6;
    const int ln = t & 63;

    // swizzled decode: L = xcd + 8*(cp + 8*(rp>>3)), rp%8 == xcd
    const int L  = blockIdx.x;
    const int rp = (L & 7) + ((L >> 6) << 3);   // row panel 0..511
    const int cp = (L >> 3) & 7;                // col tile  0..7
    const int m0 = rp * 128;
    const int n0 = cp * 128;

    const int wm = wv & 1, wn = wv >> 1;   // wave position in 2x2
    const int fr = ln & 15;                // fragment row
    const int qg = ln >> 4;                // granule (8 shorts) within 32-k chunk

    f32x4 acc[4][4];
#pragma unroll
    for (int i = 0; i < 4; i++)
#pragma unroll
        for (int j = 0; j < 4; j++) acc[i][j] = {0.f, 0.f, 0.f, 0.f};

    // staging decomposition: granule g = it*256 + t, g in [0,1024):
    //   row r = g>>3 (tile row), source slot s = g&7 (16B granule in 128B row)
    const unsigned short* xa = xbf + (size_t)m0 * C_;
    const unsigned short* wa = wbf + (size_t)n0 * C_;

    for (int k0 = 0; k0 < C_; k0 += 64) {
        uint4 av[4], bv4[4];
#pragma unroll
        for (int it = 0; it < 4; it++) {
            const int g = it * 256 + t;
            const int r = g >> 3, s = g & 7;
            av[it]  = *(const uint4*)(xa + (size_t)r * C_ + k0 + s * 8);
            bv4[it] = *(const uint4*)(wa + (size_t)r * C_ + k0 + s * 8);
        }
        if (k0) __syncthreads();   // prev iter's fragment reads done
#pragma unroll
        for (int it = 0; it < 4; it++) {
            const int g = it * 256 + t;
            const int r = g >> 3, s = g & 7;
            const int slot = s ^ (r & 7);
            *(uint4*)&As[r * 64 + slot * 8] = av[it];
            *(uint4*)&Bs[r * 64 + slot * 8] = bv4[it];
        }
        __syncthreads();

        short8 af[4][2], bfr[4][2];
#pragma unroll
        for (int i = 0; i < 4; i++) {
            const int r = wm * 64 + i * 16 + fr;           // r&7 == fr&7
#pragma unroll
            for (int kk = 0; kk < 2; kk++) {
                const int slot = (kk * 4 + qg) ^ (fr & 7);
                af[i][kk] = *(const short8*)&As[r * 64 + slot * 8];
            }
        }
#pragma unroll
        for (int j = 0; j < 4; j++) {
            const int r = wn * 64 + j * 16 + fr;
#pragma unroll
            for (int kk = 0; kk < 2; kk++) {
                const int slot = (kk * 4 + qg) ^ (fr & 7);
                bfr[j][kk] = *(const short8*)&Bs[r * 64 + slot * 8];
            }
        }
#pragma unroll
        for (int i = 0; i < 4; i++)
#pragma unroll
            for (int j = 0; j < 4; j++)
#pragma unroll
                for (int kk = 0; kk < 2; kk++)
                    acc[i][j] = __builtin_amdgcn_mfma_f32_16x16x32_bf16(
                        af[i][kk], bfr[j][kk], acc[i][j], 0, 0, 0);
    }

    __hip_bfloat16* dst;
    int oc0;
    if (n0 < C_) { dst = qws; oc0 = n0; }
    else         { dst = kws; oc0 = n0 - C_; }
    float bv[4];
#pragma unroll
    for (int j = 0; j < 4; j++) bv[j] = bias[n0 + wn * 64 + j * 16 + fr];
    const int rb = (ln >> 4) * 4;
#pragma unroll
    for (int i = 0; i < 4; i++) {
#pragma unroll
        for (int r = 0; r < 4; r++) {
            const size_t m = (size_t)(m0 + wm * 64 + i * 16 + rb + r);
#pragma unroll
            for (int j = 0; j < 4; j++) {
                const int oc = oc0 + wn * 64 + j * 16 + fr;
                float v = acc[i][j][r] + bv[j];
                v = (v > 0.f) ? (v + 1.f) : __expf(v);   // elu(v)+1
                dst[m * C_ + oc] = __float2bfloat16(v);
            }
        }
    }
}

// ---------------------------------------------------------------------------
// Kernel 2: split-N partial kv + kmean, atomic fp32 accumulate.
// NOTE: stores kv TRANSPOSED: kvT[e][d] (B-operand layout for out_mfma).
// ---------------------------------------------------------------------------
__global__ __launch_bounds__(256) void kv_partial(
    const __hip_bfloat16* __restrict__ kws, const float* __restrict__ x,
    float* __restrict__ kvT, float* __restrict__ kmean)
{
    __shared__ float kt[32][64];
    __shared__ float vt[32][64];
    const int t  = threadIdx.x;
    const int s  = blockIdx.x;       // N chunk 0..15
    const int bh = blockIdx.y;       // 0..63
    const int b  = bh >> 3, h = bh & 7;
    const int td = t >> 4, te = t & 15;
    const int kr = t >> 3;
    const int kc = (t & 7) * 8;
    const int vr = t >> 4;
    const int vc = (t & 15) * 4;

    const size_t base = (size_t)b * N_ * C_ + h * HD_;

    float acc[4][4];
    float ksum[4] = {0.f, 0.f, 0.f, 0.f};
#pragma unroll
    for (int i = 0; i < 4; i++)
#pragma unroll
        for (int j = 0; j < 4; j++) acc[i][j] = 0.f;

    const int nstart = s * (N_ / 16);
    for (int n0 = nstart; n0 < nstart + N_ / 16; n0 += 32) {
        uint4  ku = *(const uint4*)&kws[base + (size_t)(n0 + kr) * C_ + kc];
        float4 v0 = *(const float4*)&x[base + (size_t)(n0 + vr) * C_ + vc];
        float4 v1 = *(const float4*)&x[base + (size_t)(n0 + vr + 16) * C_ + vc];
        __syncthreads();
        kt[kr][kc + 0] = bf2f(ku.x & 0xffffu); kt[kr][kc + 1] = bf2f(ku.x >> 16);
        kt[kr][kc + 2] = bf2f(ku.y & 0xffffu); kt[kr][kc + 3] = bf2f(ku.y >> 16);
        kt[kr][kc + 4] = bf2f(ku.z & 0xffffu); kt[kr][kc + 5] = bf2f(ku.z >> 16);
        kt[kr][kc + 6] = bf2f(ku.w & 0xffffu); kt[kr][kc + 7] = bf2f(ku.w >> 16);
        *(float4*)&vt[vr][vc]      = v0;
        *(float4*)&vt[vr + 16][vc] = v1;
        __syncthreads();
#pragma unroll
        for (int nn = 0; nn < 32; nn++) {
            float4 kd = *(const float4*)&kt[nn][td * 4];
            float4 ve = *(const float4*)&vt[nn][te * 4];
            float kr4[4] = {kd.x, kd.y, kd.z, kd.w};
            float vr4[4] = {ve.x, ve.y, ve.z, ve.w};
#pragma unroll
            for (int i = 0; i < 4; i++)
#pragma unroll
                for (int j = 0; j < 4; j++) acc[i][j] += kr4[i] * vr4[j];
            ksum[0] += kd.x; ksum[1] += kd.y; ksum[2] += kd.z; ksum[3] += kd.w;
        }
    }

    // transposed store: kvT[e][d] += acc[i][j] where d=td*4+i, e=te*4+j
    float* kvp = kvT + (size_t)bh * HD_ * HD_;
#pragma unroll
    for (int i = 0; i < 4; i++)
#pragma unroll
        for (int j = 0; j < 4; j++)
            atomicAdd(&kvp[(te * 4 + j) * HD_ + td * 4 + i], acc[i][j]);
    if (te == 0) {
#pragma unroll
        for (int i = 0; i < 4; i++)
            atomicAdd(&kmean[bh * HD_ + td * 4 + i], ksum[i] * (1.0f / N_));
    }
}

// ---------------------------------------------------------------------------
// Kernel 3: out[b,n,h*64+e] = z[n] * (q @ kv)[n,e] + lepe(x)   via MFMA.
// 128 tokens x 64 cols per block; grid (N/128, B*H) = (64,64).
// qs/kvs bf16 in LDS with 72-short row stride (2-way bank pattern = free,
// 16B-aligned for ds_read_b128). Wave wv owns 32 tokens (2 bands of 16).
// ---------------------------------------------------------------------------
__global__ __launch_bounds__(256, 2) void out_mfma(
    const __hip_bfloat16* __restrict__ qws, const float* __restrict__ x,
    const float* __restrict__ kvT, const float* __restrict__ kmean,
    const float* __restrict__ lw, const float* __restrict__ lb,
    float* __restrict__ out)
{
    __shared__ __align__(16) unsigned short qs[128][72];   // q tokens x d
    __shared__ __align__(16) unsigned short kvs[64][72];   // kvT: e x d
    __shared__ float xs[130][68];                          // lepe halo tile
    __shared__ float zz[128];
    __shared__ float pz[128][2];
    __shared__ float kms[64];
    __shared__ float lw0[64], lw1[64], lw2[64], lbs[64];

    const int t  = threadIdx.x;
    const int n0 = blockIdx.x * 128;
    const int bh = blockIdx.y;
    const int b  = bh >> 3, h = bh & 7;

    // --- staging ---
    {   // q: 128x64 bf16 = 1024 x (8 shorts)
        const __hip_bfloat16* qp = qws + ((size_t)b * N_ + n0) * C_ + h * HD_;
        for (int i = t; i < 1024; i += 256) {
            const int r = i >> 3, c8 = (i & 7) * 8;
            uint4 u = *(const uint4*)&qp[(size_t)r * C_ + c8];
            *(uint4*)&qs[r][c8] = u;
        }
    }
    {   // kvT fp32 -> bf16 LDS, straight copy (already transposed in ws)
        const float* kvp = kvT + (size_t)bh * 4096;
        for (int i = t; i < 2048; i += 256) {
            const int e = i >> 5, d0 = (i & 31) * 2;
            float2 v = *(const float2*)&kvp[e * 64 + d0];
            *(unsigned*)&kvs[e][d0] = f2bf(v.x) | (f2bf(v.y) << 16);
        }
    }
    {   // x halo tile: 130 rows x 64 cols fp32
        for (int i = t; i < 130 * 16; i += 256) {
            const int r = i >> 4, c4 = (i & 15) * 4;
            const int n = n0 - 1 + r;
            float4 v = make_float4(0.f, 0.f, 0.f, 0.f);
            if (n >= 0 && n < N_)
                v = *(const float4*)&x[((size_t)b * N_ + n) * C_ + h * HD_ + c4];
            *(float4*)&xs[r][c4] = v;
        }
    }
    if (t < 64) {
        const int c = h * HD_ + t;
        lw0[t] = lw[c * 3 + 0];
        lw1[t] = lw[c * 3 + 1];
        lw2[t] = lw[c * 3 + 2];
        lbs[t] = lb[c];
        kms[t] = kmean[bh * HD_ + t];
    }
    __syncthreads();

    // --- z = 1/(q . kmean + eps), 2 threads per token ---
    {
        const int nn = t >> 1, d0 = (t & 1) * 32;
        float s = 0.f;
        for (int d = d0; d < d0 + 32; d++) s += bf2f(qs[nn][d]) * kms[d];
        pz[nn][t & 1] = s;
    }
    __syncthreads();
    if (t < 128) zz[t] = 1.0f / (pz[t][0] + pz[t][1] + 1e-6f);
    __syncthreads();

    // --- MFMA: wave wv -> tokens [wv*32, wv*32+32) ---
    const int wv = t >> 6, ln = t & 63;
    const int fr = ln & 15;
    const int fk = (ln >> 4) * 8;
    const int r0 = wv * 32;

    f32x4 acc[2][4];
#pragma unroll
    for (int bd = 0; bd < 2; bd++)
#pragma unroll
        for (int c = 0; c < 4; c++) acc[bd][c] = {0.f, 0.f, 0.f, 0.f};

    short8 af[2][2], bfr[4][2];
#pragma unroll
    for (int bd = 0; bd < 2; bd++)
#pragma unroll
        for (int kk = 0; kk < 2; kk++)
            af[bd][kk] = *(const short8*)&qs[r0 + bd * 16 + fr][kk * 32 + fk];
#pragma unroll
    for (int c = 0; c < 4; c++)
#pragma unroll
        for (int kk = 0; kk < 2; kk++)
            bfr[c][kk] = *(const short8*)&kvs[c * 16 + fr][kk * 32 + fk];
#pragma unroll
    for (int bd = 0; bd < 2; bd++)
#pragma unroll
        for (int c = 0; c < 4; c++)
#pragma unroll
            for (int kk = 0; kk < 2; kk++)
                acc[bd][c] = __builtin_amdgcn_mfma_f32_16x16x32_bf16(
                    af[bd][kk], bfr[c][kk], acc[bd][c], 0, 0, 0);

    // --- epilogue: *z + lepe, scalar stores (16-lane 64B segments) ---
    const int rb = (ln >> 4) * 4;
#pragma unroll
    for (int bd = 0; bd < 2; bd++) {
#pragma unroll
        for (int c = 0; c < 4; c++) {
            const int e = c * 16 + fr;
            const float w0 = lw0[e], w1 = lw1[e], w2 = lw2[e], bb = lbs[e];
#pragma unroll
            for (int r = 0; r < 4; r++) {
                const int nn = r0 + bd * 16 + rb + r;
                const float le = xs[nn][e] * w0 + xs[nn + 1][e] * w1
                               + xs[nn + 2][e] * w2 + bb;
                out[((size_t)b * N_ + n0 + nn) * C_ + h * HD_ + e] =
                    acc[bd][c][r] * zz[nn] + le;
            }
        }
    }
}

// ---------------------------------------------------------------------------
extern "C" void kernel_launch(void* const* d_in, const int* in_sizes, int n_in,
                              void* d_out, int out_size, void* d_ws, size_t ws_size,
                              hipStream_t stream)
{
    const float* x      = (const float*)d_in[0];
    const float* qk_w   = (const float*)d_in[1];
    const float* qk_b   = (const float*)d_in[2];
    const float* lepe_w = (const float*)d_in[3];
    const float* lepe_b = (const float*)d_in[4];
    float* out = (float*)d_out;

    // Workspace (135.3 MB):
    //   q  bf16 [M, C]        67.1 MB
    //   k  bf16 [M, C]        67.1 MB
    //   kvT f32 [64][64][64]   1 MB  (atomic-accum, transposed [e][d])
    //   kmean f32 [64][64]    16 KB
    // wbf (bf16 qk_w, 1 MB) ALIASES the kvT region: it is only live during
    // gemm_qk_mfma; kvT's memset happens after the GEMM on the same stream.
    // xbf (bf16 x, 67 MB) lives in d_out: dead until out_mfma overwrites it.
    char* ws = (char*)d_ws;
    __hip_bfloat16* qws = (__hip_bfloat16*)ws;
    __hip_bfloat16* kws = qws + (size_t)M_ * C_;
    float* kvT   = (float*)(ws + 2 * (size_t)M_ * C_ * sizeof(__hip_bfloat16));
    float* kmean = kvT + (size_t)64 * HD_ * HD_;
    unsigned short* wbf = (unsigned short*)kvT;   // alias, dead after gemm
    unsigned short* xbf = (unsigned short*)d_out; // alias, dead before out_mfma

    conv_w_bf16<<<256, 256, 0, stream>>>(qk_w, wbf);
    conv_x_bf16<<<M_ * C_ / (256 * 8), 256, 0, stream>>>(x, xbf);
    gemm_qk_mfma<<<4096, 256, 0, stream>>>(xbf, wbf, qk_b, qws, kws);
    hipMemsetAsync(kvT, 0, (size_t)(64 * HD_ * HD_ + 64 * HD_) * sizeof(float),
                   stream);
    kv_partial<<<dim3(16, 64), 256, 0, stream>>>(kws, x, kvT, kmean);
    out_mfma<<<dim3(N_ / 128, B_ * H_), 256, 0, stream>>>(
        qws, x, kvT, kmean, lepe_w, lepe_b, out);
}

// Round 5
// 514.313 us; speedup vs baseline: 1.3959x; 1.3959x over previous
//
#include <hip/hip_runtime.h>
#include <hip/hip_bf16.h>

// Problem constants (from reference setup_inputs)
#define B_    8
#define N_    8192
#define C_    512
#define H_    8
#define HD_   64
#define M_    (B_ * N_)      // 65536 rows
#define TWO_C 1024

typedef short short8 __attribute__((ext_vector_type(8)));   // 8 bf16 (4 VGPRs)
typedef float f32x4  __attribute__((ext_vector_type(4)));   // MFMA accumulator

__device__ __forceinline__ float bf2f(unsigned v) {
    return __uint_as_float(v << 16);
}

__device__ __forceinline__ unsigned f2bf(float f) {
    union { __hip_bfloat16 b; unsigned short u; } cv;
    cv.b = __float2bfloat16(f);
    return (unsigned)cv.u;
}

__device__ __forceinline__ uint2 pack4(float4 f) {
    uint2 r;
    r.x = f2bf(f.x) | (f2bf(f.y) << 16);
    r.y = f2bf(f.z) | (f2bf(f.w) << 16);
    return r;
}

// ---------------------------------------------------------------------------
// Kernel 0a: qk_w fp32 -> bf16 (1MB out).  Kernel 0b: x fp32 -> bf16 (64MB out,
// lives in d_out which is dead until out_mfma overwrites it).
// ---------------------------------------------------------------------------
__global__ __launch_bounds__(256) void conv_w_bf16(
    const float* __restrict__ w, unsigned short* __restrict__ wbf)
{
    const int i = (blockIdx.x * 256 + threadIdx.x) * 8;
    float4 a = *(const float4*)(w + i);
    float4 b = *(const float4*)(w + i + 4);
    uint2 pa = pack4(a), pb = pack4(b);
    *(uint4*)(wbf + i) = make_uint4(pa.x, pa.y, pb.x, pb.y);
}

__global__ __launch_bounds__(256) void conv_x_bf16(
    const float* __restrict__ x, unsigned short* __restrict__ xbf)
{
    const size_t i = ((size_t)blockIdx.x * 256 + threadIdx.x) * 8;
    float4 a = *(const float4*)(x + i);
    float4 b = *(const float4*)(x + i + 4);
    uint2 pa = pack4(a), pb = pack4(b);
    *(uint4*)(xbf + i) = make_uint4(pa.x, pa.y, pb.x, pb.y);
}

// ---------------------------------------------------------------------------
// Kernel 1: qk = x @ qk_w^T + qk_b ; q = elu(.)+1 ; k = elu(.)+1  (bf16 out)
// MFMA bf16 GEMM: 128x128 tile, BK=64, 4 waves (2x2), 4x4 16x16x32 per wave.
// Reg-staged with NAMED scalar uint4s (r4's av[4]/bv4[4] arrays hit rule #20:
// alloca -> 1.1GB scratch spill traffic; named scalars like r1 don't spill).
// Thread t stages rows sr+{0,32,64,96} (sr=t>>3), constant source slot
// ss=t&7, constant dest slot ss^(sr&7).
// LDS XOR swizzle verified conflict-free on HW (r4: SQ_LDS_BANK_CONFLICT=0):
// LDS slot q of row r holds global granule q^(r&7); fragment read uses
// slot=(kk*4+qg)^(fr&7).  128B rows -> 8-lane groups cover all 8 bank-quads.
// XCD swizzle: all 8 column tiles of a row panel land on the same XCD
// (xcd = L&7 = rp%8 under round-robin dispatch), x panel L2-resident.
// ---------------------------------------------------------------------------
__global__ __launch_bounds__(256, 2) void gemm_qk_mfma(
    const unsigned short* __restrict__ xbf, const unsigned short* __restrict__ wbf,
    const float* __restrict__ bias,
    __hip_bfloat16* __restrict__ qws, __hip_bfloat16* __restrict__ kws)
{
    __shared__ __align__(16) unsigned short As[128 * 64];  // [row][k] bf16, 16KB
    __shared__ __align__(16) unsigned short Bs[128 * 64];

    const int t  = threadIdx.x;
    const int wv = t >> 6;
    const int ln = t & 63;

    // swizzled decode: L = xcd + 8*(cp + 8*(rp>>3)), rp%8 == xcd
    const int L  = blockIdx.x;
    const int rp = (L & 7) + ((L >> 6) << 3);   // row panel 0..511
    const int cp = (L >> 3) & 7;                // col tile  0..7
    const int m0 = rp * 128;
    const int n0 = cp * 128;

    const int wm = wv & 1, wn = wv >> 1;   // wave position in 2x2
    const int fr = ln & 15;                // fragment row
    const int qg = ln >> 4;                // granule (8 shorts) within 32-k chunk

    // staging: row sr (+32/+64/+96), source slot ss, dest slot ds = ss^(sr&7)
    const int sr = t >> 3;
    const int ss = t & 7;
    const int ds = ss ^ (sr & 7);

    f32x4 acc[4][4];
#pragma unroll
    for (int i = 0; i < 4; i++)
#pragma unroll
        for (int j = 0; j < 4; j++) acc[i][j] = {0.f, 0.f, 0.f, 0.f};

    const unsigned short* xa = xbf + (size_t)(m0 + sr) * C_ + ss * 8;
    const unsigned short* wa = wbf + (size_t)(n0 + sr) * C_ + ss * 8;
    unsigned short* const la = &As[sr * 64 + ds * 8];
    unsigned short* const lb = &Bs[sr * 64 + ds * 8];

    for (int k0 = 0; k0 < C_; k0 += 64) {
        uint4 a0 = *(const uint4*)(xa + k0);
        uint4 a1 = *(const uint4*)(xa + k0 + (size_t)32 * C_);
        uint4 a2 = *(const uint4*)(xa + k0 + (size_t)64 * C_);
        uint4 a3 = *(const uint4*)(xa + k0 + (size_t)96 * C_);
        uint4 b0 = *(const uint4*)(wa + k0);
        uint4 b1 = *(const uint4*)(wa + k0 + (size_t)32 * C_);
        uint4 b2 = *(const uint4*)(wa + k0 + (size_t)64 * C_);
        uint4 b3 = *(const uint4*)(wa + k0 + (size_t)96 * C_);
        if (k0) __syncthreads();   // prev iter's fragment reads done
        *(uint4*)(la + 0 * 32 * 64) = a0;
        *(uint4*)(la + 1 * 32 * 64) = a1;
        *(uint4*)(la + 2 * 32 * 64) = a2;
        *(uint4*)(la + 3 * 32 * 64) = a3;
        *(uint4*)(lb + 0 * 32 * 64) = b0;
        *(uint4*)(lb + 1 * 32 * 64) = b1;
        *(uint4*)(lb + 2 * 32 * 64) = b2;
        *(uint4*)(lb + 3 * 32 * 64) = b3;
        __syncthreads();

        short8 af[4][2], bfr[4][2];
#pragma unroll
        for (int i = 0; i < 4; i++) {
            const int r = wm * 64 + i * 16 + fr;           // r&7 == fr&7
#pragma unroll
            for (int kk = 0; kk < 2; kk++) {
                const int slot = (kk * 4 + qg) ^ (fr & 7);
                af[i][kk] = *(const short8*)&As[r * 64 + slot * 8];
            }
        }
#pragma unroll
        for (int j = 0; j < 4; j++) {
            const int r = wn * 64 + j * 16 + fr;
#pragma unroll
            for (int kk = 0; kk < 2; kk++) {
                const int slot = (kk * 4 + qg) ^ (fr & 7);
                bfr[j][kk] = *(const short8*)&Bs[r * 64 + slot * 8];
            }
        }
#pragma unroll
        for (int i = 0; i < 4; i++)
#pragma unroll
            for (int j = 0; j < 4; j++)
#pragma unroll
                for (int kk = 0; kk < 2; kk++)
                    acc[i][j] = __builtin_amdgcn_mfma_f32_16x16x32_bf16(
                        af[i][kk], bfr[j][kk], acc[i][j], 0, 0, 0);
    }

    __hip_bfloat16* dst;
    int oc0;
    if (n0 < C_) { dst = qws; oc0 = n0; }
    else         { dst = kws; oc0 = n0 - C_; }
    float bv[4];
#pragma unroll
    for (int j = 0; j < 4; j++) bv[j] = bias[n0 + wn * 64 + j * 16 + fr];
    const int rb = (ln >> 4) * 4;
#pragma unroll
    for (int i = 0; i < 4; i++) {
#pragma unroll
        for (int r = 0; r < 4; r++) {
            const size_t m = (size_t)(m0 + wm * 64 + i * 16 + rb + r);
#pragma unroll
            for (int j = 0; j < 4; j++) {
                const int oc = oc0 + wn * 64 + j * 16 + fr;
                float v = acc[i][j][r] + bv[j];
                v = (v > 0.f) ? (v + 1.f) : __expf(v);   // elu(v)+1
                dst[m * C_ + oc] = __float2bfloat16(v);
            }
        }
    }
}

// ---------------------------------------------------------------------------
// Kernel 2: split-N partial kv + kmean, atomic fp32 accumulate.
// NOTE: stores kv TRANSPOSED: kvT[e][d] (B-operand layout for out_mfma).
// ---------------------------------------------------------------------------
__global__ __launch_bounds__(256) void kv_partial(
    const __hip_bfloat16* __restrict__ kws, const float* __restrict__ x,
    float* __restrict__ kvT, float* __restrict__ kmean)
{
    __shared__ float kt[32][64];
    __shared__ float vt[32][64];
    const int t  = threadIdx.x;
    const int s  = blockIdx.x;       // N chunk 0..15
    const int bh = blockIdx.y;       // 0..63
    const int b  = bh >> 3, h = bh & 7;
    const int td = t >> 4, te = t & 15;
    const int kr = t >> 3;
    const int kc = (t & 7) * 8;
    const int vr = t >> 4;
    const int vc = (t & 15) * 4;

    const size_t base = (size_t)b * N_ * C_ + h * HD_;

    float acc[4][4];
    float ksum[4] = {0.f, 0.f, 0.f, 0.f};
#pragma unroll
    for (int i = 0; i < 4; i++)
#pragma unroll
        for (int j = 0; j < 4; j++) acc[i][j] = 0.f;

    const int nstart = s * (N_ / 16);
    for (int n0 = nstart; n0 < nstart + N_ / 16; n0 += 32) {
        uint4  ku = *(const uint4*)&kws[base + (size_t)(n0 + kr) * C_ + kc];
        float4 v0 = *(const float4*)&x[base + (size_t)(n0 + vr) * C_ + vc];
        float4 v1 = *(const float4*)&x[base + (size_t)(n0 + vr + 16) * C_ + vc];
        __syncthreads();
        kt[kr][kc + 0] = bf2f(ku.x & 0xffffu); kt[kr][kc + 1] = bf2f(ku.x >> 16);
        kt[kr][kc + 2] = bf2f(ku.y & 0xffffu); kt[kr][kc + 3] = bf2f(ku.y >> 16);
        kt[kr][kc + 4] = bf2f(ku.z & 0xffffu); kt[kr][kc + 5] = bf2f(ku.z >> 16);
        kt[kr][kc + 6] = bf2f(ku.w & 0xffffu); kt[kr][kc + 7] = bf2f(ku.w >> 16);
        *(float4*)&vt[vr][vc]      = v0;
        *(float4*)&vt[vr + 16][vc] = v1;
        __syncthreads();
#pragma unroll
        for (int nn = 0; nn < 32; nn++) {
            float4 kd = *(const float4*)&kt[nn][td * 4];
            float4 ve = *(const float4*)&vt[nn][te * 4];
            float kr4[4] = {kd.x, kd.y, kd.z, kd.w};
            float vr4[4] = {ve.x, ve.y, ve.z, ve.w};
#pragma unroll
            for (int i = 0; i < 4; i++)
#pragma unroll
                for (int j = 0; j < 4; j++) acc[i][j] += kr4[i] * vr4[j];
            ksum[0] += kd.x; ksum[1] += kd.y; ksum[2] += kd.z; ksum[3] += kd.w;
        }
    }

    // transposed store: kvT[e][d] += acc[i][j] where d=td*4+i, e=te*4+j
    float* kvp = kvT + (size_t)bh * HD_ * HD_;
#pragma unroll
    for (int i = 0; i < 4; i++)
#pragma unroll
        for (int j = 0; j < 4; j++)
            atomicAdd(&kvp[(te * 4 + j) * HD_ + td * 4 + i], acc[i][j]);
    if (te == 0) {
#pragma unroll
        for (int i = 0; i < 4; i++)
            atomicAdd(&kmean[bh * HD_ + td * 4 + i], ksum[i] * (1.0f / N_));
    }
}

// ---------------------------------------------------------------------------
// Kernel 3: out[b,n,h*64+e] = z[n] * (q @ kv)[n,e] + lepe(x)   via MFMA.
// 128 tokens x 64 cols per block; grid (N/128, B*H) = (64,64).
// qs/kvs bf16 in LDS with 72-short row stride (2-way bank pattern = free,
// 16B-aligned for ds_read_b128). Wave wv owns 32 tokens (2 bands of 16).
// ---------------------------------------------------------------------------
__global__ __launch_bounds__(256, 2) void out_mfma(
    const __hip_bfloat16* __restrict__ qws, const float* __restrict__ x,
    const float* __restrict__ kvT, const float* __restrict__ kmean,
    const float* __restrict__ lw, const float* __restrict__ lb,
    float* __restrict__ out)
{
    __shared__ __align__(16) unsigned short qs[128][72];   // q tokens x d
    __shared__ __align__(16) unsigned short kvs[64][72];   // kvT: e x d
    __shared__ float xs[130][68];                          // lepe halo tile
    __shared__ float zz[128];
    __shared__ float pz[128][2];
    __shared__ float kms[64];
    __shared__ float lw0[64], lw1[64], lw2[64], lbs[64];

    const int t  = threadIdx.x;
    const int n0 = blockIdx.x * 128;
    const int bh = blockIdx.y;
    const int b  = bh >> 3, h = bh & 7;

    // --- staging ---
    {   // q: 128x64 bf16 = 1024 x (8 shorts)
        const __hip_bfloat16* qp = qws + ((size_t)b * N_ + n0) * C_ + h * HD_;
        for (int i = t; i < 1024; i += 256) {
            const int r = i >> 3, c8 = (i & 7) * 8;
            uint4 u = *(const uint4*)&qp[(size_t)r * C_ + c8];
            *(uint4*)&qs[r][c8] = u;
        }
    }
    {   // kvT fp32 -> bf16 LDS, straight copy (already transposed in ws)
        const float* kvp = kvT + (size_t)bh * 4096;
        for (int i = t; i < 2048; i += 256) {
            const int e = i >> 5, d0 = (i & 31) * 2;
            float2 v = *(const float2*)&kvp[e * 64 + d0];
            *(unsigned*)&kvs[e][d0] = f2bf(v.x) | (f2bf(v.y) << 16);
        }
    }
    {   // x halo tile: 130 rows x 64 cols fp32
        for (int i = t; i < 130 * 16; i += 256) {
            const int r = i >> 4, c4 = (i & 15) * 4;
            const int n = n0 - 1 + r;
            float4 v = make_float4(0.f, 0.f, 0.f, 0.f);
            if (n >= 0 && n < N_)
                v = *(const float4*)&x[((size_t)b * N_ + n) * C_ + h * HD_ + c4];
            *(float4*)&xs[r][c4] = v;
        }
    }
    if (t < 64) {
        const int c = h * HD_ + t;
        lw0[t] = lw[c * 3 + 0];
        lw1[t] = lw[c * 3 + 1];
        lw2[t] = lw[c * 3 + 2];
        lbs[t] = lb[c];
        kms[t] = kmean[bh * HD_ + t];
    }
    __syncthreads();

    // --- z = 1/(q . kmean + eps), 2 threads per token ---
    {
        const int nn = t >> 1, d0 = (t & 1) * 32;
        float s = 0.f;
        for (int d = d0; d < d0 + 32; d++) s += bf2f(qs[nn][d]) * kms[d];
        pz[nn][t & 1] = s;
    }
    __syncthreads();
    if (t < 128) zz[t] = 1.0f / (pz[t][0] + pz[t][1] + 1e-6f);
    __syncthreads();

    // --- MFMA: wave wv -> tokens [wv*32, wv*32+32) ---
    const int wv = t >> 6, ln = t & 63;
    const int fr = ln & 15;
    const int fk = (ln >> 4) * 8;
    const int r0 = wv * 32;

    f32x4 acc[2][4];
#pragma unroll
    for (int bd = 0; bd < 2; bd++)
#pragma unroll
        for (int c = 0; c < 4; c++) acc[bd][c] = {0.f, 0.f, 0.f, 0.f};

    short8 af[2][2], bfr[4][2];
#pragma unroll
    for (int bd = 0; bd < 2; bd++)
#pragma unroll
        for (int kk = 0; kk < 2; kk++)
            af[bd][kk] = *(const short8*)&qs[r0 + bd * 16 + fr][kk * 32 + fk];
#pragma unroll
    for (int c = 0; c < 4; c++)
#pragma unroll
        for (int kk = 0; kk < 2; kk++)
            bfr[c][kk] = *(const short8*)&kvs[c * 16 + fr][kk * 32 + fk];
#pragma unroll
    for (int bd = 0; bd < 2; bd++)
#pragma unroll
        for (int c = 0; c < 4; c++)
#pragma unroll
            for (int kk = 0; kk < 2; kk++)
                acc[bd][c] = __builtin_amdgcn_mfma_f32_16x16x32_bf16(
                    af[bd][kk], bfr[c][kk], acc[bd][c], 0, 0, 0);

    // --- epilogue: *z + lepe, scalar stores (16-lane 64B segments) ---
    const int rb = (ln >> 4) * 4;
#pragma unroll
    for (int bd = 0; bd < 2; bd++) {
#pragma unroll
        for (int c = 0; c < 4; c++) {
            const int e = c * 16 + fr;
            const float w0 = lw0[e], w1 = lw1[e], w2 = lw2[e], bb = lbs[e];
#pragma unroll
            for (int r = 0; r < 4; r++) {
                const int nn = r0 + bd * 16 + rb + r;
                const float le = xs[nn][e] * w0 + xs[nn + 1][e] * w1
                               + xs[nn + 2][e] * w2 + bb;
                out[((size_t)b * N_ + n0 + nn) * C_ + h * HD_ + e] =
                    acc[bd][c][r] * zz[nn] + le;
            }
        }
    }
}

// ---------------------------------------------------------------------------
extern "C" void kernel_launch(void* const* d_in, const int* in_sizes, int n_in,
                              void* d_out, int out_size, void* d_ws, size_t ws_size,
                              hipStream_t stream)
{
    const float* x      = (const float*)d_in[0];
    const float* qk_w   = (const float*)d_in[1];
    const float* qk_b   = (const float*)d_in[2];
    const float* lepe_w = (const float*)d_in[3];
    const float* lepe_b = (const float*)d_in[4];
    float* out = (float*)d_out;

    // Workspace (135.3 MB):
    //   q  bf16 [M, C]        67.1 MB
    //   k  bf16 [M, C]        67.1 MB
    //   kvT f32 [64][64][64]   1 MB  (atomic-accum, transposed [e][d])
    //   kmean f32 [64][64]    16 KB
    // wbf (bf16 qk_w, 1 MB) ALIASES the kvT region: it is only live during
    // gemm_qk_mfma; kvT's memset happens after the GEMM on the same stream.
    // xbf (bf16 x, 67 MB) lives in d_out: dead until out_mfma overwrites it.
    char* ws = (char*)d_ws;
    __hip_bfloat16* qws = (__hip_bfloat16*)ws;
    __hip_bfloat16* kws = qws + (size_t)M_ * C_;
    float* kvT   = (float*)(ws + 2 * (size_t)M_ * C_ * sizeof(__hip_bfloat16));
    float* kmean = kvT + (size_t)64 * HD_ * HD_;
    unsigned short* wbf = (unsigned short*)kvT;   // alias, dead after gemm
    unsigned short* xbf = (unsigned short*)d_out; // alias, dead before out_mfma

    conv_w_bf16<<<256, 256, 0, stream>>>(qk_w, wbf);
    conv_x_bf16<<<M_ * C_ / (256 * 8), 256, 0, stream>>>(x, xbf);
    gemm_qk_mfma<<<4096, 256, 0, stream>>>(xbf, wbf, qk_b, qws, kws);
    hipMemsetAsync(kvT, 0, (size_t)(64 * HD_ * HD_ + 64 * HD_) * sizeof(float),
                   stream);
    kv_partial<<<dim3(16, 64), 256, 0, stream>>>(kws, x, kvT, kmean);
    out_mfma<<<dim3(N_ / 128, B_ * H_), 256, 0, stream>>>(
        qws, x, kvT, kmean, lepe_w, lepe_b, out);
}

// Round 6
// 497.500 us; speedup vs baseline: 1.4431x; 1.0338x over previous
//
#include <hip/hip_runtime.h>
#include <hip/hip_bf16.h>

// Problem constants (from reference setup_inputs)
#define B_    8
#define N_    8192
#define C_    512
#define H_    8
#define HD_   64
#define M_    (B_ * N_)      // 65536 rows
#define TWO_C 1024

typedef short short8 __attribute__((ext_vector_type(8)));   // 8 bf16 (4 VGPRs)
typedef float f32x4  __attribute__((ext_vector_type(4)));   // MFMA accumulator

__device__ __forceinline__ float bf2f(unsigned v) {
    return __uint_as_float(v << 16);
}

__device__ __forceinline__ unsigned f2bf(float f) {
    union { __hip_bfloat16 b; unsigned short u; } cv;
    cv.b = __float2bfloat16(f);
    return (unsigned)cv.u;
}

__device__ __forceinline__ uint2 pack4(float4 f) {
    uint2 r;
    r.x = f2bf(f.x) | (f2bf(f.y) << 16);
    r.y = f2bf(f.z) | (f2bf(f.w) << 16);
    return r;
}

__device__ __forceinline__ short8 pack8(float4 lo, float4 hi) {
    uint2 a = pack4(lo), b = pack4(hi);
    union { uint4 u; short8 s; } cv;
    cv.u = make_uint4(a.x, a.y, b.x, b.y);
    return cv.s;
}

// ---------------------------------------------------------------------------
// Kernel 0a: qk_w fp32 -> bf16 (1MB out).  Kernel 0b: x fp32 -> bf16 (64MB out,
// lives in d_out which is dead until out_mfma overwrites it).
// ---------------------------------------------------------------------------
__global__ __launch_bounds__(256) void conv_w_bf16(
    const float* __restrict__ w, unsigned short* __restrict__ wbf)
{
    const int i = (blockIdx.x * 256 + threadIdx.x) * 8;
    float4 a = *(const float4*)(w + i);
    float4 b = *(const float4*)(w + i + 4);
    uint2 pa = pack4(a), pb = pack4(b);
    *(uint4*)(wbf + i) = make_uint4(pa.x, pa.y, pb.x, pb.y);
}

__global__ __launch_bounds__(256) void conv_x_bf16(
    const float* __restrict__ x, unsigned short* __restrict__ xbf)
{
    const size_t i = ((size_t)blockIdx.x * 256 + threadIdx.x) * 8;
    float4 a = *(const float4*)(x + i);
    float4 b = *(const float4*)(x + i + 4);
    uint2 pa = pack4(a), pb = pack4(b);
    *(uint4*)(xbf + i) = make_uint4(pa.x, pa.y, pb.x, pb.y);
}

// ---------------------------------------------------------------------------
// Kernel 1: qk = x @ qk_w^T + qk_b ; q = elu(.)+1 ; k = elu(.)+1  (bf16 out)
// MFMA bf16 GEMM: 128x128 tile, BK=64, 4 waves (2x2), 4x4 16x16x32 per wave.
// Reg-staged with NAMED scalar uint4s (rule #20: arrays -> alloca -> scratch).
// LDS XOR swizzle verified conflict-free on HW (r4/r5: SQ_LDS_BANK_CONFLICT=0).
// XCD swizzle: all 8 column tiles of a row panel land on the same XCD.
// ---------------------------------------------------------------------------
__global__ __launch_bounds__(256, 2) void gemm_qk_mfma(
    const unsigned short* __restrict__ xbf, const unsigned short* __restrict__ wbf,
    const float* __restrict__ bias,
    __hip_bfloat16* __restrict__ qws, __hip_bfloat16* __restrict__ kws)
{
    __shared__ __align__(16) unsigned short As[128 * 64];  // [row][k] bf16, 16KB
    __shared__ __align__(16) unsigned short Bs[128 * 64];

    const int t  = threadIdx.x;
    const int wv = t >> 6;
    const int ln = t & 63;

    // swizzled decode: L = xcd + 8*(cp + 8*(rp>>3)), rp%8 == xcd
    const int L  = blockIdx.x;
    const int rp = (L & 7) + ((L >> 6) << 3);   // row panel 0..511
    const int cp = (L >> 3) & 7;                // col tile  0..7
    const int m0 = rp * 128;
    const int n0 = cp * 128;

    const int wm = wv & 1, wn = wv >> 1;   // wave position in 2x2
    const int fr = ln & 15;                // fragment row
    const int qg = ln >> 4;                // granule (8 shorts) within 32-k chunk

    // staging: row sr (+32/+64/+96), source slot ss, dest slot ds = ss^(sr&7)
    const int sr = t >> 3;
    const int ss = t & 7;
    const int ds = ss ^ (sr & 7);

    f32x4 acc[4][4];
#pragma unroll
    for (int i = 0; i < 4; i++)
#pragma unroll
        for (int j = 0; j < 4; j++) acc[i][j] = {0.f, 0.f, 0.f, 0.f};

    const unsigned short* xa = xbf + (size_t)(m0 + sr) * C_ + ss * 8;
    const unsigned short* wa = wbf + (size_t)(n0 + sr) * C_ + ss * 8;
    unsigned short* const la = &As[sr * 64 + ds * 8];
    unsigned short* const lb = &Bs[sr * 64 + ds * 8];

    for (int k0 = 0; k0 < C_; k0 += 64) {
        uint4 a0 = *(const uint4*)(xa + k0);
        uint4 a1 = *(const uint4*)(xa + k0 + (size_t)32 * C_);
        uint4 a2 = *(const uint4*)(xa + k0 + (size_t)64 * C_);
        uint4 a3 = *(const uint4*)(xa + k0 + (size_t)96 * C_);
        uint4 b0 = *(const uint4*)(wa + k0);
        uint4 b1 = *(const uint4*)(wa + k0 + (size_t)32 * C_);
        uint4 b2 = *(const uint4*)(wa + k0 + (size_t)64 * C_);
        uint4 b3 = *(const uint4*)(wa + k0 + (size_t)96 * C_);
        if (k0) __syncthreads();   // prev iter's fragment reads done
        *(uint4*)(la + 0 * 32 * 64) = a0;
        *(uint4*)(la + 1 * 32 * 64) = a1;
        *(uint4*)(la + 2 * 32 * 64) = a2;
        *(uint4*)(la + 3 * 32 * 64) = a3;
        *(uint4*)(lb + 0 * 32 * 64) = b0;
        *(uint4*)(lb + 1 * 32 * 64) = b1;
        *(uint4*)(lb + 2 * 32 * 64) = b2;
        *(uint4*)(lb + 3 * 32 * 64) = b3;
        __syncthreads();

        short8 af[4][2], bfr[4][2];
#pragma unroll
        for (int i = 0; i < 4; i++) {
            const int r = wm * 64 + i * 16 + fr;           // r&7 == fr&7
#pragma unroll
            for (int kk = 0; kk < 2; kk++) {
                const int slot = (kk * 4 + qg) ^ (fr & 7);
                af[i][kk] = *(const short8*)&As[r * 64 + slot * 8];
            }
        }
#pragma unroll
        for (int j = 0; j < 4; j++) {
            const int r = wn * 64 + j * 16 + fr;
#pragma unroll
            for (int kk = 0; kk < 2; kk++) {
                const int slot = (kk * 4 + qg) ^ (fr & 7);
                bfr[j][kk] = *(const short8*)&Bs[r * 64 + slot * 8];
            }
        }
#pragma unroll
        for (int i = 0; i < 4; i++)
#pragma unroll
            for (int j = 0; j < 4; j++)
#pragma unroll
                for (int kk = 0; kk < 2; kk++)
                    acc[i][j] = __builtin_amdgcn_mfma_f32_16x16x32_bf16(
                        af[i][kk], bfr[j][kk], acc[i][j], 0, 0, 0);
    }

    __hip_bfloat16* dst;
    int oc0;
    if (n0 < C_) { dst = qws; oc0 = n0; }
    else         { dst = kws; oc0 = n0 - C_; }
    float bv[4];
#pragma unroll
    for (int j = 0; j < 4; j++) bv[j] = bias[n0 + wn * 64 + j * 16 + fr];
    const int rb = (ln >> 4) * 4;
#pragma unroll
    for (int i = 0; i < 4; i++) {
#pragma unroll
        for (int r = 0; r < 4; r++) {
            const size_t m = (size_t)(m0 + wm * 64 + i * 16 + rb + r);
#pragma unroll
            for (int j = 0; j < 4; j++) {
                const int oc = oc0 + wn * 64 + j * 16 + fr;
                float v = acc[i][j][r] + bv[j];
                v = (v > 0.f) ? (v + 1.f) : __expf(v);   // elu(v)+1
                dst[m * C_ + oc] = __float2bfloat16(v);
            }
        }
    }
}

// ---------------------------------------------------------------------------
// Kernel 2: split-N partial kv + kmean, atomic fp32 accumulate.
// NOTE: stores kv TRANSPOSED: kvT[e][d] (B-operand layout for out_mfma).
// ---------------------------------------------------------------------------
__global__ __launch_bounds__(256) void kv_partial(
    const __hip_bfloat16* __restrict__ kws, const float* __restrict__ x,
    float* __restrict__ kvT, float* __restrict__ kmean)
{
    __shared__ float kt[32][64];
    __shared__ float vt[32][64];
    const int t  = threadIdx.x;
    const int s  = blockIdx.x;       // N chunk 0..15
    const int bh = blockIdx.y;       // 0..63
    const int b  = bh >> 3, h = bh & 7;
    const int td = t >> 4, te = t & 15;
    const int kr = t >> 3;
    const int kc = (t & 7) * 8;
    const int vr = t >> 4;
    const int vc = (t & 15) * 4;

    const size_t base = (size_t)b * N_ * C_ + h * HD_;

    float acc[4][4];
    float ksum[4] = {0.f, 0.f, 0.f, 0.f};
#pragma unroll
    for (int i = 0; i < 4; i++)
#pragma unroll
        for (int j = 0; j < 4; j++) acc[i][j] = 0.f;

    const int nstart = s * (N_ / 16);
    for (int n0 = nstart; n0 < nstart + N_ / 16; n0 += 32) {
        uint4  ku = *(const uint4*)&kws[base + (size_t)(n0 + kr) * C_ + kc];
        float4 v0 = *(const float4*)&x[base + (size_t)(n0 + vr) * C_ + vc];
        float4 v1 = *(const float4*)&x[base + (size_t)(n0 + vr + 16) * C_ + vc];
        __syncthreads();
        kt[kr][kc + 0] = bf2f(ku.x & 0xffffu); kt[kr][kc + 1] = bf2f(ku.x >> 16);
        kt[kr][kc + 2] = bf2f(ku.y & 0xffffu); kt[kr][kc + 3] = bf2f(ku.y >> 16);
        kt[kr][kc + 4] = bf2f(ku.z & 0xffffu); kt[kr][kc + 5] = bf2f(ku.z >> 16);
        kt[kr][kc + 6] = bf2f(ku.w & 0xffffu); kt[kr][kc + 7] = bf2f(ku.w >> 16);
        *(float4*)&vt[vr][vc]      = v0;
        *(float4*)&vt[vr + 16][vc] = v1;
        __syncthreads();
#pragma unroll
        for (int nn = 0; nn < 32; nn++) {
            float4 kd = *(const float4*)&kt[nn][td * 4];
            float4 ve = *(const float4*)&vt[nn][te * 4];
            float kr4[4] = {kd.x, kd.y, kd.z, kd.w};
            float vr4[4] = {ve.x, ve.y, ve.z, ve.w};
#pragma unroll
            for (int i = 0; i < 4; i++)
#pragma unroll
                for (int j = 0; j < 4; j++) acc[i][j] += kr4[i] * vr4[j];
            ksum[0] += kd.x; ksum[1] += kd.y; ksum[2] += kd.z; ksum[3] += kd.w;
        }
    }

    // transposed store: kvT[e][d] += acc[i][j] where d=td*4+i, e=te*4+j
    float* kvp = kvT + (size_t)bh * HD_ * HD_;
#pragma unroll
    for (int i = 0; i < 4; i++)
#pragma unroll
        for (int j = 0; j < 4; j++)
            atomicAdd(&kvp[(te * 4 + j) * HD_ + td * 4 + i], acc[i][j]);
    if (te == 0) {
#pragma unroll
        for (int i = 0; i < 4; i++)
            atomicAdd(&kmean[bh * HD_ + td * 4 + i], ksum[i] * (1.0f / N_));
    }
}

// ---------------------------------------------------------------------------
// Kernel 3: out[b,n,h*64+e] = z[n] * (q @ kv)[n,e] + lepe(x)   via MFMA.
// 128 tokens x 64 cols per block; grid (N/128, B*H) = (64,64).
// r6 rework (r5 showed latency-bound: Occ 20%, LDS 66KB -> 2 blk/CU):
//  - xs halo stored bf16 (35->17.7KB); kvs LDS dropped -- kv+kmean fragments
//    loaded global->reg (kvT 16KB/head, L2-hot).  LDS ~37KB -> 4 blk/CU.
//  - z fused into MFMA: kmean as virtual B-column (fr==0 lane holds kmean,
//    else 0), z broadcast via shfl from col-0 lane.  Removes serial z-phase
//    and 2 of 3 barriers: single-barrier kernel.
// ---------------------------------------------------------------------------
__global__ __launch_bounds__(256, 4) void out_mfma(
    const __hip_bfloat16* __restrict__ qws, const float* __restrict__ x,
    const float* __restrict__ kvT, const float* __restrict__ kmean,
    const float* __restrict__ lw, const float* __restrict__ lb,
    float* __restrict__ out)
{
    __shared__ __align__(16) unsigned short qs[128][72];   // q tokens x d, 18.4KB
    __shared__ __align__(16) unsigned short xsb[130][68];  // lepe halo bf16, 17.7KB
    __shared__ float lw0[64], lw1[64], lw2[64], lbs[64];

    const int t  = threadIdx.x;
    const int n0 = blockIdx.x * 128;
    const int bh = blockIdx.y;
    const int b  = bh >> 3, h = bh & 7;

    const int wv = t >> 6, ln = t & 63;
    const int fr = ln & 15;
    const int fk = (ln >> 4) * 8;

    // --- LDS staging ---
    {   // q: 128x64 bf16 = 1024 x (8 shorts)
        const __hip_bfloat16* qp = qws + ((size_t)b * N_ + n0) * C_ + h * HD_;
        for (int i = t; i < 1024; i += 256) {
            const int r = i >> 3, c8 = (i & 7) * 8;
            uint4 u = *(const uint4*)&qp[(size_t)r * C_ + c8];
            *(uint4*)&qs[r][c8] = u;
        }
    }
    {   // x halo tile fp32 -> bf16: 130 rows x 64 cols
        for (int i = t; i < 130 * 16; i += 256) {
            const int r = i >> 4, c4 = (i & 15) * 4;
            const int n = n0 - 1 + r;
            float4 v = make_float4(0.f, 0.f, 0.f, 0.f);
            if (n >= 0 && n < N_)
                v = *(const float4*)&x[((size_t)b * N_ + n) * C_ + h * HD_ + c4];
            *(uint2*)&xsb[r][c4] = pack4(v);
        }
    }
    if (t < 64) {
        const int c = h * HD_ + t;
        lw0[t] = lw[c * 3 + 0];
        lw1[t] = lw[c * 3 + 1];
        lw2[t] = lw[c * 3 + 2];
        lbs[t] = lb[c];
    }

    // --- kv + kmean fragments: global -> reg (L2-hot), fp32 -> bf16 ---
    short8 bfr[4][2], bz[2];
    {
        const float* kvp = kvT + (size_t)bh * 4096;
#pragma unroll
        for (int c = 0; c < 4; c++)
#pragma unroll
            for (int kk = 0; kk < 2; kk++) {
                const float* p = kvp + (c * 16 + fr) * 64 + kk * 32 + fk;
                float4 lo = *(const float4*)p;
                float4 hi = *(const float4*)(p + 4);
                bfr[c][kk] = pack8(lo, hi);
            }
        const float* kmp = kmean + bh * HD_;
        const short8 z8 = {0, 0, 0, 0, 0, 0, 0, 0};
#pragma unroll
        for (int kk = 0; kk < 2; kk++) {
            const float* p = kmp + kk * 32 + fk;
            float4 lo = *(const float4*)p;
            float4 hi = *(const float4*)(p + 4);
            short8 pk = pack8(lo, hi);
            bz[kk] = (fr == 0) ? pk : z8;
        }
    }

    __syncthreads();

    // --- MFMA: wave wv -> tokens [wv*32, wv*32+32); z fused as extra col ---
    const int r0 = wv * 32;

    f32x4 acc[2][4], zacc[2];
#pragma unroll
    for (int bd = 0; bd < 2; bd++) {
        zacc[bd] = {0.f, 0.f, 0.f, 0.f};
#pragma unroll
        for (int c = 0; c < 4; c++) acc[bd][c] = {0.f, 0.f, 0.f, 0.f};
    }

    short8 af[2][2];
#pragma unroll
    for (int bd = 0; bd < 2; bd++)
#pragma unroll
        for (int kk = 0; kk < 2; kk++)
            af[bd][kk] = *(const short8*)&qs[r0 + bd * 16 + fr][kk * 32 + fk];

#pragma unroll
    for (int bd = 0; bd < 2; bd++) {
#pragma unroll
        for (int c = 0; c < 4; c++)
#pragma unroll
            for (int kk = 0; kk < 2; kk++)
                acc[bd][c] = __builtin_amdgcn_mfma_f32_16x16x32_bf16(
                    af[bd][kk], bfr[c][kk], acc[bd][c], 0, 0, 0);
#pragma unroll
        for (int kk = 0; kk < 2; kk++)
            zacc[bd] = __builtin_amdgcn_mfma_f32_16x16x32_bf16(
                af[bd][kk], bz[kk], zacc[bd], 0, 0, 0);
    }

    // --- epilogue: z broadcast (col-0 lane of 16-group), *z + lepe ---
    const int rb = (ln >> 4) * 4;
#pragma unroll
    for (int bd = 0; bd < 2; bd++) {
        float zr[4];
#pragma unroll
        for (int r = 0; r < 4; r++)
            zr[r] = 1.0f / (__shfl(zacc[bd][r], ln & 48) + 1e-6f);
#pragma unroll
        for (int c = 0; c < 4; c++) {
            const int e = c * 16 + fr;
            const float w0 = lw0[e], w1 = lw1[e], w2 = lw2[e], bb = lbs[e];
#pragma unroll
            for (int r = 0; r < 4; r++) {
                const int nn = r0 + bd * 16 + rb + r;
                const float le = bf2f(xsb[nn][e]) * w0 + bf2f(xsb[nn + 1][e]) * w1
                               + bf2f(xsb[nn + 2][e]) * w2 + bb;
                out[((size_t)b * N_ + n0 + nn) * C_ + h * HD_ + e] =
                    acc[bd][c][r] * zr[r] + le;
            }
        }
    }
}

// ---------------------------------------------------------------------------
extern "C" void kernel_launch(void* const* d_in, const int* in_sizes, int n_in,
                              void* d_out, int out_size, void* d_ws, size_t ws_size,
                              hipStream_t stream)
{
    const float* x      = (const float*)d_in[0];
    const float* qk_w   = (const float*)d_in[1];
    const float* qk_b   = (const float*)d_in[2];
    const float* lepe_w = (const float*)d_in[3];
    const float* lepe_b = (const float*)d_in[4];
    float* out = (float*)d_out;

    // Workspace (135.3 MB):
    //   q  bf16 [M, C]        67.1 MB
    //   k  bf16 [M, C]        67.1 MB
    //   kvT f32 [64][64][64]   1 MB  (atomic-accum, transposed [e][d])
    //   kmean f32 [64][64]    16 KB
    // wbf (bf16 qk_w, 1 MB) ALIASES the kvT region: it is only live during
    // gemm_qk_mfma; kvT's memset happens after the GEMM on the same stream.
    // xbf (bf16 x, 67 MB) lives in d_out: dead until out_mfma overwrites it.
    char* ws = (char*)d_ws;
    __hip_bfloat16* qws = (__hip_bfloat16*)ws;
    __hip_bfloat16* kws = qws + (size_t)M_ * C_;
    float* kvT   = (float*)(ws + 2 * (size_t)M_ * C_ * sizeof(__hip_bfloat16));
    float* kmean = kvT + (size_t)64 * HD_ * HD_;
    unsigned short* wbf = (unsigned short*)kvT;   // alias, dead after gemm
    unsigned short* xbf = (unsigned short*)d_out; // alias, dead before out_mfma

    conv_w_bf16<<<256, 256, 0, stream>>>(qk_w, wbf);
    conv_x_bf16<<<M_ * C_ / (256 * 8), 256, 0, stream>>>(x, xbf);
    gemm_qk_mfma<<<4096, 256, 0, stream>>>(xbf, wbf, qk_b, qws, kws);
    hipMemsetAsync(kvT, 0, (size_t)(64 * HD_ * HD_ + 64 * HD_) * sizeof(float),
                   stream);
    kv_partial<<<dim3(16, 64), 256, 0, stream>>>(kws, x, kvT, kmean);
    out_mfma<<<dim3(N_ / 128, B_ * H_), 256, 0, stream>>>(
        qws, x, kvT, kmean, lepe_w, lepe_b, out);
}

// Round 7
// 423.828 us; speedup vs baseline: 1.6939x; 1.1738x over previous
//
#include <hip/hip_runtime.h>
#include <hip/hip_bf16.h>

// Problem constants (from reference setup_inputs)
#define B_    8
#define N_    8192
#define C_    512
#define H_    8
#define HD_   64
#define M_    (B_ * N_)      // 65536 rows
#define TWO_C 1024

typedef short short8 __attribute__((ext_vector_type(8)));   // 8 bf16 (4 VGPRs)
typedef float f32x4  __attribute__((ext_vector_type(4)));   // MFMA accumulator

__device__ __forceinline__ float bf2f(unsigned v) {
    return __uint_as_float(v << 16);
}

__device__ __forceinline__ unsigned f2bf(float f) {
    union { __hip_bfloat16 b; unsigned short u; } cv;
    cv.b = __float2bfloat16(f);
    return (unsigned)cv.u;
}

__device__ __forceinline__ uint2 pack4(float4 f) {
    uint2 r;
    r.x = f2bf(f.x) | (f2bf(f.y) << 16);
    r.y = f2bf(f.z) | (f2bf(f.w) << 16);
    return r;
}

__device__ __forceinline__ short8 pack8(float4 lo, float4 hi) {
    uint2 a = pack4(lo), b = pack4(hi);
    union { uint4 u; short8 s; } cv;
    cv.u = make_uint4(a.x, a.y, b.x, b.y);
    return cv.s;
}

// ---------------------------------------------------------------------------
// Kernel 0a: qk_w fp32 -> bf16 (1MB out).  Kernel 0b: x fp32 -> bf16 (64MB out,
// lives in d_out which is dead until out_mfma overwrites it).
// ---------------------------------------------------------------------------
__global__ __launch_bounds__(256) void conv_w_bf16(
    const float* __restrict__ w, unsigned short* __restrict__ wbf)
{
    const int i = (blockIdx.x * 256 + threadIdx.x) * 8;
    float4 a = *(const float4*)(w + i);
    float4 b = *(const float4*)(w + i + 4);
    uint2 pa = pack4(a), pb = pack4(b);
    *(uint4*)(wbf + i) = make_uint4(pa.x, pa.y, pb.x, pb.y);
}

__global__ __launch_bounds__(256) void conv_x_bf16(
    const float* __restrict__ x, unsigned short* __restrict__ xbf)
{
    const size_t i = ((size_t)blockIdx.x * 256 + threadIdx.x) * 8;
    float4 a = *(const float4*)(x + i);
    float4 b = *(const float4*)(x + i + 4);
    uint2 pa = pack4(a), pb = pack4(b);
    *(uint4*)(xbf + i) = make_uint4(pa.x, pa.y, pb.x, pb.y);
}

// ---------------------------------------------------------------------------
// Kernel 1: qk = x @ qk_w^T + qk_b ; q = elu(.)+1 ; k = elu(.)+1  (bf16 out)
// MFMA bf16 GEMM: 128x128 tile, BK=64, 4 waves (2x2), 4x4 16x16x32 per wave.
// Reg-staged with NAMED scalar uint4s (rule #20: arrays -> alloca -> scratch).
// LDS XOR swizzle verified conflict-free on HW (r4/r5: SQ_LDS_BANK_CONFLICT=0).
// XCD swizzle: all 8 column tiles of a row panel land on the same XCD.
// ---------------------------------------------------------------------------
__global__ __launch_bounds__(256, 2) void gemm_qk_mfma(
    const unsigned short* __restrict__ xbf, const unsigned short* __restrict__ wbf,
    const float* __restrict__ bias,
    __hip_bfloat16* __restrict__ qws, __hip_bfloat16* __restrict__ kws)
{
    __shared__ __align__(16) unsigned short As[128 * 64];  // [row][k] bf16, 16KB
    __shared__ __align__(16) unsigned short Bs[128 * 64];

    const int t  = threadIdx.x;
    const int wv = t >> 6;
    const int ln = t & 63;

    // swizzled decode: L = xcd + 8*(cp + 8*(rp>>3)), rp%8 == xcd
    const int L  = blockIdx.x;
    const int rp = (L & 7) + ((L >> 6) << 3);   // row panel 0..511
    const int cp = (L >> 3) & 7;                // col tile  0..7
    const int m0 = rp * 128;
    const int n0 = cp * 128;

    const int wm = wv & 1, wn = wv >> 1;   // wave position in 2x2
    const int fr = ln & 15;                // fragment row
    const int qg = ln >> 4;                // granule (8 shorts) within 32-k chunk

    // staging: row sr (+32/+64/+96), source slot ss, dest slot ds = ss^(sr&7)
    const int sr = t >> 3;
    const int ss = t & 7;
    const int ds = ss ^ (sr & 7);

    f32x4 acc[4][4];
#pragma unroll
    for (int i = 0; i < 4; i++)
#pragma unroll
        for (int j = 0; j < 4; j++) acc[i][j] = {0.f, 0.f, 0.f, 0.f};

    const unsigned short* xa = xbf + (size_t)(m0 + sr) * C_ + ss * 8;
    const unsigned short* wa = wbf + (size_t)(n0 + sr) * C_ + ss * 8;
    unsigned short* const la = &As[sr * 64 + ds * 8];
    unsigned short* const lb = &Bs[sr * 64 + ds * 8];

    for (int k0 = 0; k0 < C_; k0 += 64) {
        uint4 a0 = *(const uint4*)(xa + k0);
        uint4 a1 = *(const uint4*)(xa + k0 + (size_t)32 * C_);
        uint4 a2 = *(const uint4*)(xa + k0 + (size_t)64 * C_);
        uint4 a3 = *(const uint4*)(xa + k0 + (size_t)96 * C_);
        uint4 b0 = *(const uint4*)(wa + k0);
        uint4 b1 = *(const uint4*)(wa + k0 + (size_t)32 * C_);
        uint4 b2 = *(const uint4*)(wa + k0 + (size_t)64 * C_);
        uint4 b3 = *(const uint4*)(wa + k0 + (size_t)96 * C_);
        if (k0) __syncthreads();   // prev iter's fragment reads done
        *(uint4*)(la + 0 * 32 * 64) = a0;
        *(uint4*)(la + 1 * 32 * 64) = a1;
        *(uint4*)(la + 2 * 32 * 64) = a2;
        *(uint4*)(la + 3 * 32 * 64) = a3;
        *(uint4*)(lb + 0 * 32 * 64) = b0;
        *(uint4*)(lb + 1 * 32 * 64) = b1;
        *(uint4*)(lb + 2 * 32 * 64) = b2;
        *(uint4*)(lb + 3 * 32 * 64) = b3;
        __syncthreads();

        short8 af[4][2], bfr[4][2];
#pragma unroll
        for (int i = 0; i < 4; i++) {
            const int r = wm * 64 + i * 16 + fr;           // r&7 == fr&7
#pragma unroll
            for (int kk = 0; kk < 2; kk++) {
                const int slot = (kk * 4 + qg) ^ (fr & 7);
                af[i][kk] = *(const short8*)&As[r * 64 + slot * 8];
            }
        }
#pragma unroll
        for (int j = 0; j < 4; j++) {
            const int r = wn * 64 + j * 16 + fr;
#pragma unroll
            for (int kk = 0; kk < 2; kk++) {
                const int slot = (kk * 4 + qg) ^ (fr & 7);
                bfr[j][kk] = *(const short8*)&Bs[r * 64 + slot * 8];
            }
        }
#pragma unroll
        for (int i = 0; i < 4; i++)
#pragma unroll
            for (int j = 0; j < 4; j++)
#pragma unroll
                for (int kk = 0; kk < 2; kk++)
                    acc[i][j] = __builtin_amdgcn_mfma_f32_16x16x32_bf16(
                        af[i][kk], bfr[j][kk], acc[i][j], 0, 0, 0);
    }

    __hip_bfloat16* dst;
    int oc0;
    if (n0 < C_) { dst = qws; oc0 = n0; }
    else         { dst = kws; oc0 = n0 - C_; }
    float bv[4];
#pragma unroll
    for (int j = 0; j < 4; j++) bv[j] = bias[n0 + wn * 64 + j * 16 + fr];
    const int rb = (ln >> 4) * 4;
#pragma unroll
    for (int i = 0; i < 4; i++) {
#pragma unroll
        for (int r = 0; r < 4; r++) {
            const size_t m = (size_t)(m0 + wm * 64 + i * 16 + rb + r);
#pragma unroll
            for (int j = 0; j < 4; j++) {
                const int oc = oc0 + wn * 64 + j * 16 + fr;
                float v = acc[i][j][r] + bv[j];
                v = (v > 0.f) ? (v + 1.f) : __expf(v);   // elu(v)+1
                dst[m * C_ + oc] = __float2bfloat16(v);
            }
        }
    }
}

// ---------------------------------------------------------------------------
// Kernel 2: split-N partial kvT + kmean via MFMA (r7 rework; r6 was VALU
// outer-product at MfmaUtil=0, VALUBusy 40%, 103us).
// kvT[e][d] = sum_n v[n][e] k[n][d]:  A = v^T (e rows), B = k^T (d rows),
// K-axis = n.  Transposed LDS tiles [64][72] bf16:
//   - ST=72 shorts: frag ds_read_b128 dword = 4*((fr+qg+4kk)%8) -> 8 lanes
//     per 4-bank slot = conflict-free minimum; staged writes 2 lanes/bank.
//   - transposed staging: wave wv stages d/e rows 16wv..16wv+16, lane = n;
//     16 scalar b16 writes/thread/tile (same count as r6's unpack writes).
//   - v read from xbf (bf16 x in d_out, still live): half the v fetch.
// kmean free via virtual ones-row in A (wm==0 waves, +4 MFMA/tile):
//   row0 of extra A-frag = 1.0 -> D[0][d] = sum_n k[n][d].
// Each wave owns a 32x32 quadrant (wm = e-half, wn = d-half): 8 MFMA/tile.
// Epilogue: fp32 atomicAdd into kvT[e][d] / kmean (split-N reduction).
// ---------------------------------------------------------------------------
__global__ __launch_bounds__(256, 4) void kv_partial(
    const __hip_bfloat16* __restrict__ kws, const unsigned short* __restrict__ xbf,
    float* __restrict__ kvT, float* __restrict__ kmean)
{
    __shared__ __align__(16) unsigned short ktT[64][72];   // [d][n] bf16, 9.2KB
    __shared__ __align__(16) unsigned short vtT[64][72];   // [e][n] bf16, 9.2KB

    const int t  = threadIdx.x;
    const int s  = blockIdx.x;       // N chunk 0..15
    const int bh = blockIdx.y;       // 0..63
    const int b  = bh >> 3, h = bh & 7;
    const int wv = t >> 6, ln = t & 63;
    const int wm = wv & 1, wn = wv >> 1;   // wm: e-half, wn: d-half
    const int fr = ln & 15, qg = ln >> 4;
    const int sd = wv * 16;                 // staged d/e row block

    const unsigned short* kp0 = (const unsigned short*)kws + h * HD_ + sd;
    const unsigned short* vp0 = xbf + h * HD_ + sd;

    f32x4 acc[2][2], zacc[2];
#pragma unroll
    for (int i = 0; i < 2; i++) {
        zacc[i] = {0.f, 0.f, 0.f, 0.f};
#pragma unroll
        for (int j = 0; j < 2; j++) acc[i][j] = {0.f, 0.f, 0.f, 0.f};
    }

    // virtual ones A-row (row fr==0 of the frag = 1.0 bf16, rest 0)
    short8 ones;
    {
        const unsigned short o = (fr == 0) ? 0x3F80 : 0;
#pragma unroll
        for (int j = 0; j < 8; j++) ones[j] = (short)o;
    }

    const int nstart = s * (N_ / 16);
    for (int tt = 0; tt < 8; tt++) {
        const size_t row = (size_t)b * N_ + nstart + tt * 64 + ln;
        uint4 ku0 = *(const uint4*)(kp0 + row * C_);
        uint4 ku1 = *(const uint4*)(kp0 + row * C_ + 8);
        uint4 vu0 = *(const uint4*)(vp0 + row * C_);
        uint4 vu1 = *(const uint4*)(vp0 + row * C_ + 8);
        if (tt) __syncthreads();   // prev frag reads done before overwrite
        {   // transposed write: ktT[sd+j][ln], vtT[sd+j][ln]
            unsigned short* kc = &ktT[sd][ln];
            unsigned short* vc = &vtT[sd][ln];
            kc[0 * 72]  = (unsigned short)ku0.x; kc[1 * 72]  = (unsigned short)(ku0.x >> 16);
            kc[2 * 72]  = (unsigned short)ku0.y; kc[3 * 72]  = (unsigned short)(ku0.y >> 16);
            kc[4 * 72]  = (unsigned short)ku0.z; kc[5 * 72]  = (unsigned short)(ku0.z >> 16);
            kc[6 * 72]  = (unsigned short)ku0.w; kc[7 * 72]  = (unsigned short)(ku0.w >> 16);
            kc[8 * 72]  = (unsigned short)ku1.x; kc[9 * 72]  = (unsigned short)(ku1.x >> 16);
            kc[10 * 72] = (unsigned short)ku1.y; kc[11 * 72] = (unsigned short)(ku1.y >> 16);
            kc[12 * 72] = (unsigned short)ku1.z; kc[13 * 72] = (unsigned short)(ku1.z >> 16);
            kc[14 * 72] = (unsigned short)ku1.w; kc[15 * 72] = (unsigned short)(ku1.w >> 16);
            vc[0 * 72]  = (unsigned short)vu0.x; vc[1 * 72]  = (unsigned short)(vu0.x >> 16);
            vc[2 * 72]  = (unsigned short)vu0.y; vc[3 * 72]  = (unsigned short)(vu0.y >> 16);
            vc[4 * 72]  = (unsigned short)vu0.z; vc[5 * 72]  = (unsigned short)(vu0.z >> 16);
            vc[6 * 72]  = (unsigned short)vu0.w; vc[7 * 72]  = (unsigned short)(vu0.w >> 16);
            vc[8 * 72]  = (unsigned short)vu1.x; vc[9 * 72]  = (unsigned short)(vu1.x >> 16);
            vc[10 * 72] = (unsigned short)vu1.y; vc[11 * 72] = (unsigned short)(vu1.y >> 16);
            vc[12 * 72] = (unsigned short)vu1.z; vc[13 * 72] = (unsigned short)(vu1.z >> 16);
            vc[14 * 72] = (unsigned short)vu1.w; vc[15 * 72] = (unsigned short)(vu1.w >> 16);
        }
        __syncthreads();

        short8 av[2][2], bk[2][2];
#pragma unroll
        for (int i = 0; i < 2; i++)
#pragma unroll
            for (int kk = 0; kk < 2; kk++) {
                av[i][kk] = *(const short8*)&vtT[wm * 32 + i * 16 + fr][kk * 32 + qg * 8];
                bk[i][kk] = *(const short8*)&ktT[wn * 32 + i * 16 + fr][kk * 32 + qg * 8];
            }
#pragma unroll
        for (int i = 0; i < 2; i++)
#pragma unroll
            for (int j = 0; j < 2; j++)
#pragma unroll
                for (int kk = 0; kk < 2; kk++)
                    acc[i][j] = __builtin_amdgcn_mfma_f32_16x16x32_bf16(
                        av[i][kk], bk[j][kk], acc[i][j], 0, 0, 0);
        if (wm == 0) {
#pragma unroll
            for (int j = 0; j < 2; j++)
#pragma unroll
                for (int kk = 0; kk < 2; kk++)
                    zacc[j] = __builtin_amdgcn_mfma_f32_16x16x32_bf16(
                        ones, bk[j][kk], zacc[j], 0, 0, 0);
        }
    }

    // epilogue: D layout col=fr (d), row=qg*4+r (e)
    float* kvp = kvT + (size_t)bh * HD_ * HD_;
#pragma unroll
    for (int i = 0; i < 2; i++)
#pragma unroll
        for (int j = 0; j < 2; j++)
#pragma unroll
            for (int r = 0; r < 4; r++) {
                const int e = wm * 32 + i * 16 + qg * 4 + r;
                const int d = wn * 32 + j * 16 + fr;
                atomicAdd(&kvp[e * HD_ + d], acc[i][j][r]);
            }
    if (wm == 0 && ln < 16) {
#pragma unroll
        for (int j = 0; j < 2; j++)
            atomicAdd(&kmean[bh * HD_ + wn * 32 + j * 16 + fr],
                      zacc[j][0] * (1.0f / N_));
    }
}

// ---------------------------------------------------------------------------
// Kernel 3: out[b,n,h*64+e] = z[n] * (q @ kv)[n,e] + lepe(x)   via MFMA.
// 128 tokens x 64 cols per block; grid (N/128, B*H) = (64,64).
// Single-barrier kernel; z fused into MFMA via kmean virtual B-column.
// ---------------------------------------------------------------------------
__global__ __launch_bounds__(256, 4) void out_mfma(
    const __hip_bfloat16* __restrict__ qws, const float* __restrict__ x,
    const float* __restrict__ kvT, const float* __restrict__ kmean,
    const float* __restrict__ lw, const float* __restrict__ lb,
    float* __restrict__ out)
{
    __shared__ __align__(16) unsigned short qs[128][72];   // q tokens x d, 18.4KB
    __shared__ __align__(16) unsigned short xsb[130][68];  // lepe halo bf16, 17.7KB
    __shared__ float lw0[64], lw1[64], lw2[64], lbs[64];

    const int t  = threadIdx.x;
    const int n0 = blockIdx.x * 128;
    const int bh = blockIdx.y;
    const int b  = bh >> 3, h = bh & 7;

    const int wv = t >> 6, ln = t & 63;
    const int fr = ln & 15;
    const int fk = (ln >> 4) * 8;

    // --- LDS staging ---
    {   // q: 128x64 bf16 = 1024 x (8 shorts)
        const __hip_bfloat16* qp = qws + ((size_t)b * N_ + n0) * C_ + h * HD_;
        for (int i = t; i < 1024; i += 256) {
            const int r = i >> 3, c8 = (i & 7) * 8;
            uint4 u = *(const uint4*)&qp[(size_t)r * C_ + c8];
            *(uint4*)&qs[r][c8] = u;
        }
    }
    {   // x halo tile fp32 -> bf16: 130 rows x 64 cols
        for (int i = t; i < 130 * 16; i += 256) {
            const int r = i >> 4, c4 = (i & 15) * 4;
            const int n = n0 - 1 + r;
            float4 v = make_float4(0.f, 0.f, 0.f, 0.f);
            if (n >= 0 && n < N_)
                v = *(const float4*)&x[((size_t)b * N_ + n) * C_ + h * HD_ + c4];
            *(uint2*)&xsb[r][c4] = pack4(v);
        }
    }
    if (t < 64) {
        const int c = h * HD_ + t;
        lw0[t] = lw[c * 3 + 0];
        lw1[t] = lw[c * 3 + 1];
        lw2[t] = lw[c * 3 + 2];
        lbs[t] = lb[c];
    }

    // --- kv + kmean fragments: global -> reg (L2-hot), fp32 -> bf16 ---
    short8 bfr[4][2], bz[2];
    {
        const float* kvp = kvT + (size_t)bh * 4096;
#pragma unroll
        for (int c = 0; c < 4; c++)
#pragma unroll
            for (int kk = 0; kk < 2; kk++) {
                const float* p = kvp + (c * 16 + fr) * 64 + kk * 32 + fk;
                float4 lo = *(const float4*)p;
                float4 hi = *(const float4*)(p + 4);
                bfr[c][kk] = pack8(lo, hi);
            }
        const float* kmp = kmean + bh * HD_;
        const short8 z8 = {0, 0, 0, 0, 0, 0, 0, 0};
#pragma unroll
        for (int kk = 0; kk < 2; kk++) {
            const float* p = kmp + kk * 32 + fk;
            float4 lo = *(const float4*)p;
            float4 hi = *(const float4*)(p + 4);
            short8 pk = pack8(lo, hi);
            bz[kk] = (fr == 0) ? pk : z8;
        }
    }

    __syncthreads();

    // --- MFMA: wave wv -> tokens [wv*32, wv*32+32); z fused as extra col ---
    const int r0 = wv * 32;

    f32x4 acc[2][4], zacc[2];
#pragma unroll
    for (int bd = 0; bd < 2; bd++) {
        zacc[bd] = {0.f, 0.f, 0.f, 0.f};
#pragma unroll
        for (int c = 0; c < 4; c++) acc[bd][c] = {0.f, 0.f, 0.f, 0.f};
    }

    short8 af[2][2];
#pragma unroll
    for (int bd = 0; bd < 2; bd++)
#pragma unroll
        for (int kk = 0; kk < 2; kk++)
            af[bd][kk] = *(const short8*)&qs[r0 + bd * 16 + fr][kk * 32 + fk];

#pragma unroll
    for (int bd = 0; bd < 2; bd++) {
#pragma unroll
        for (int c = 0; c < 4; c++)
#pragma unroll
            for (int kk = 0; kk < 2; kk++)
                acc[bd][c] = __builtin_amdgcn_mfma_f32_16x16x32_bf16(
                    af[bd][kk], bfr[c][kk], acc[bd][c], 0, 0, 0);
#pragma unroll
        for (int kk = 0; kk < 2; kk++)
            zacc[bd] = __builtin_amdgcn_mfma_f32_16x16x32_bf16(
                af[bd][kk], bz[kk], zacc[bd], 0, 0, 0);
    }

    // --- epilogue: z broadcast (col-0 lane of 16-group), *z + lepe ---
    const int rb = (ln >> 4) * 4;
#pragma unroll
    for (int bd = 0; bd < 2; bd++) {
        float zr[4];
#pragma unroll
        for (int r = 0; r < 4; r++)
            zr[r] = 1.0f / (__shfl(zacc[bd][r], ln & 48) + 1e-6f);
#pragma unroll
        for (int c = 0; c < 4; c++) {
            const int e = c * 16 + fr;
            const float w0 = lw0[e], w1 = lw1[e], w2 = lw2[e], bb = lbs[e];
#pragma unroll
            for (int r = 0; r < 4; r++) {
                const int nn = r0 + bd * 16 + rb + r;
                const float le = bf2f(xsb[nn][e]) * w0 + bf2f(xsb[nn + 1][e]) * w1
                               + bf2f(xsb[nn + 2][e]) * w2 + bb;
                out[((size_t)b * N_ + n0 + nn) * C_ + h * HD_ + e] =
                    acc[bd][c][r] * zr[r] + le;
            }
        }
    }
}

// ---------------------------------------------------------------------------
extern "C" void kernel_launch(void* const* d_in, const int* in_sizes, int n_in,
                              void* d_out, int out_size, void* d_ws, size_t ws_size,
                              hipStream_t stream)
{
    const float* x      = (const float*)d_in[0];
    const float* qk_w   = (const float*)d_in[1];
    const float* qk_b   = (const float*)d_in[2];
    const float* lepe_w = (const float*)d_in[3];
    const float* lepe_b = (const float*)d_in[4];
    float* out = (float*)d_out;

    // Workspace (135.3 MB):
    //   q  bf16 [M, C]        67.1 MB
    //   k  bf16 [M, C]        67.1 MB
    //   kvT f32 [64][64][64]   1 MB  (atomic-accum, transposed [e][d])
    //   kmean f32 [64][64]    16 KB
    // wbf (bf16 qk_w, 1 MB) ALIASES the kvT region: it is only live during
    // gemm_qk_mfma; kvT's memset happens after the GEMM on the same stream.
    // xbf (bf16 x, 67 MB) lives in d_out: dead until out_mfma overwrites it
    // (kv_partial reads it BEFORE out_mfma runs -- stream-ordered).
    char* ws = (char*)d_ws;
    __hip_bfloat16* qws = (__hip_bfloat16*)ws;
    __hip_bfloat16* kws = qws + (size_t)M_ * C_;
    float* kvT   = (float*)(ws + 2 * (size_t)M_ * C_ * sizeof(__hip_bfloat16));
    float* kmean = kvT + (size_t)64 * HD_ * HD_;
    unsigned short* wbf = (unsigned short*)kvT;   // alias, dead after gemm
    unsigned short* xbf = (unsigned short*)d_out; // alias, dead before out_mfma

    conv_w_bf16<<<256, 256, 0, stream>>>(qk_w, wbf);
    conv_x_bf16<<<M_ * C_ / (256 * 8), 256, 0, stream>>>(x, xbf);
    gemm_qk_mfma<<<4096, 256, 0, stream>>>(xbf, wbf, qk_b, qws, kws);
    hipMemsetAsync(kvT, 0, (size_t)(64 * HD_ * HD_ + 64 * HD_) * sizeof(float),
                   stream);
    kv_partial<<<dim3(16, 64), 256, 0, stream>>>(kws, xbf, kvT, kmean);
    out_mfma<<<dim3(N_ / 128, B_ * H_), 256, 0, stream>>>(
        qws, x, kvT, kmean, lepe_w, lepe_b, out);
}